// Round 1
// baseline (3346.126 us; speedup 1.0000x reference)
//
#include <hip/hip_runtime.h>

// ---------------------------------------------------------------------------
// PointSampler / DevConv, restructured:
//   per layer l:  y = h @ Cl.T        (Cl = Wp[l] @ Wt[l-1], C0 = Wp[0])
//                 aggf[i] = max_{(j->i) in E} flip(y[j])    (atomic max-scatter)
//                 h_next[i][d] = aggf==0 ? 0 : unflip(aggf) - y[i][d]   (fused
//                                into the next consumer)
//   head:         out[i] = sigmoid( agg3[i] . v + b ),  v = (W_out @ Wt[2]).T
// ---------------------------------------------------------------------------

__device__ __forceinline__ unsigned flipf(float f) {
    unsigned u = __float_as_uint(f);
    return (u & 0x80000000u) ? ~u : (u | 0x80000000u);
}
__device__ __forceinline__ float unflipf(unsigned u) {
    return __uint_as_float((u & 0x80000000u) ? (u & 0x7fffffffu) : ~u);
}

// block 0: C2 = Wp[1]@Wt[0];  block 1: C3 = Wp[2]@Wt[1];  block 2: v = Wout@Wt[2]
__global__ __launch_bounds__(256) void prep_k(
    const float* __restrict__ Wp, const float* __restrict__ Wt,
    const float* __restrict__ Wout,
    float* __restrict__ C2, float* __restrict__ C3, float* __restrict__ vout)
{
    __shared__ float A[4096];
    __shared__ float B[4096];
    int tid = threadIdx.x;
    int b = blockIdx.x;
    if (b < 2) {
        const float* Ap = Wp + (size_t)(b + 1) * 4096;
        const float* Bp = Wt + (size_t)b * 4096;
        for (int i = tid; i < 4096; i += 256) { A[i] = Ap[i]; B[i] = Bp[i]; }
        __syncthreads();
        float* C = b ? C3 : C2;
        for (int i = tid; i < 4096; i += 256) {
            int d = i >> 6, k = i & 63;
            float s = 0.f;
            #pragma unroll
            for (int m = 0; m < 64; ++m) s += A[d * 64 + m] * B[m * 64 + k];
            C[i] = s;
        }
    } else {
        for (int i = tid; i < 4096; i += 256) A[i] = Wt[2 * 4096 + i];
        if (tid < 64) B[tid] = Wout[tid];
        __syncthreads();
        if (tid < 64) {
            float s = 0.f;
            #pragma unroll
            for (int m = 0; m < 64; ++m) s += B[m] * A[m * 64 + tid];
            vout[tid] = s;
        }
    }
}

// y[r][:] = in_row(r) @ C.T ; one thread per row, weight (transposed) in LDS,
// all lanes broadcast-read the same LDS address (conflict-free).
// FUSE: input row is reconstructed from (aggf, yprev) of the previous layer.
template<bool FUSE>
__global__ __launch_bounds__(256) void gemm64_k(
    const float* __restrict__ in,
    const unsigned* __restrict__ aggf,
    const float* __restrict__ yprev,
    const float* __restrict__ C,      // [64][64] row-major, C[d][k]
    float* __restrict__ out, int n)
{
    __shared__ float sCT[64 * 68];    // sCT[k*68 + d]; stride 68 keeps b128 alignment
    int tid = threadIdx.x;
    for (int i = tid; i < 4096; i += 256) {
        int d = i >> 6, k = i & 63;
        sCT[k * 68 + d] = C[i];
    }
    __syncthreads();
    int r = blockIdx.x * 256 + tid;
    if (r >= n) return;

    float xr[64];
    if (FUSE) {
        const uint4*  af = (const uint4*)(aggf + (size_t)r * 64);
        const float4* yp = (const float4*)(yprev + (size_t)r * 64);
        #pragma unroll
        for (int k4 = 0; k4 < 16; ++k4) {
            uint4 a = af[k4];
            float4 y = yp[k4];
            xr[k4 * 4 + 0] = a.x ? unflipf(a.x) - y.x : 0.f;
            xr[k4 * 4 + 1] = a.y ? unflipf(a.y) - y.y : 0.f;
            xr[k4 * 4 + 2] = a.z ? unflipf(a.z) - y.z : 0.f;
            xr[k4 * 4 + 3] = a.w ? unflipf(a.w) - y.w : 0.f;
        }
    } else {
        const float4* xp = (const float4*)(in + (size_t)r * 64);
        #pragma unroll
        for (int k4 = 0; k4 < 16; ++k4) {
            float4 v = xp[k4];
            xr[k4 * 4 + 0] = v.x; xr[k4 * 4 + 1] = v.y;
            xr[k4 * 4 + 2] = v.z; xr[k4 * 4 + 3] = v.w;
        }
    }

    float4* op = (float4*)(out + (size_t)r * 64);
    for (int dg = 0; dg < 16; ++dg) {
        float a0 = 0.f, a1 = 0.f, a2 = 0.f, a3 = 0.f;
        #pragma unroll
        for (int k = 0; k < 64; ++k) {
            float4 c = *(const float4*)&sCT[k * 68 + dg * 4];
            a0 += xr[k] * c.x;
            a1 += xr[k] * c.y;
            a2 += xr[k] * c.z;
            a3 += xr[k] * c.w;
        }
        float4 o; o.x = a0; o.y = a1; o.z = a2; o.w = a3;
        op[dg] = o;
    }
}

__global__ __launch_bounds__(256) void clear_k(unsigned* __restrict__ p, int n4)
{
    int i = blockIdx.x * 256 + threadIdx.x;
    uint4 z; z.x = 0u; z.y = 0u; z.z = 0u; z.w = 0u;
    if (i < n4) ((uint4*)p)[i] = z;
}

// one thread per (edge, 4 components): atomic max-scatter of flip(y[src]) into aggf[dst]
__global__ __launch_bounds__(256) void edge_max_k(
    const int* __restrict__ eidx,     // [2][E] (int32 view)
    const float* __restrict__ y,
    unsigned* __restrict__ aggf, int nE)
{
    int tid = threadIdx.x;
    int e   = blockIdx.x * 16 + (tid & 15);
    int c16 = tid >> 4;
    if (e >= nE) return;
    int src = eidx[e];
    int dst = eidx[nE + e];
    float4 v = ((const float4*)y)[(size_t)src * 16 + c16];
    unsigned* p = aggf + (size_t)dst * 64 + c16 * 4;
    atomicMax(p + 0, flipf(v.x));
    atomicMax(p + 1, flipf(v.y));
    atomicMax(p + 2, flipf(v.z));
    atomicMax(p + 3, flipf(v.w));
}

__global__ __launch_bounds__(256) void final_k(
    const unsigned* __restrict__ aggf, const float* __restrict__ y,
    const float* __restrict__ v, const float* __restrict__ bptr,
    float* __restrict__ out, int n)
{
    __shared__ float sv[64];
    int tid = threadIdx.x;
    if (tid < 64) sv[tid] = v[tid];
    __syncthreads();
    int r = blockIdx.x * 256 + tid;
    if (r >= n) return;
    const uint4*  af = (const uint4*)(aggf + (size_t)r * 64);
    const float4* yp = (const float4*)(y + (size_t)r * 64);
    float s = 0.f;
    #pragma unroll
    for (int k4 = 0; k4 < 16; ++k4) {
        uint4 a = af[k4];
        float4 yv = yp[k4];
        float g0 = a.x ? unflipf(a.x) - yv.x : 0.f;
        float g1 = a.y ? unflipf(a.y) - yv.y : 0.f;
        float g2 = a.z ? unflipf(a.z) - yv.z : 0.f;
        float g3 = a.w ? unflipf(a.w) - yv.w : 0.f;
        s += g0 * sv[k4 * 4 + 0] + g1 * sv[k4 * 4 + 1]
           + g2 * sv[k4 * 4 + 2] + g3 * sv[k4 * 4 + 3];
    }
    s += bptr[0];
    out[r] = 1.f / (1.f + __expf(-s));
}

extern "C" void kernel_launch(void* const* d_in, const int* in_sizes, int n_in,
                              void* d_out, int out_size, void* d_ws, size_t ws_size,
                              hipStream_t stream)
{
    const float* x     = (const float*)d_in[0];
    const int*   edges = (const int*)d_in[1];   // integers arrive as int32
    const float* Wp    = (const float*)d_in[2];
    const float* Wt    = (const float*)d_in[3];
    const float* Wout  = (const float*)d_in[4];
    const float* bout  = (const float*)d_in[5];
    const int N = in_sizes[0] / 64;             // 100000
    const int E = in_sizes[1] / 2;              // 1600000
    float* out = (float*)d_out;

    char* ws = (char*)d_ws;
    float*    ya   = (float*)ws;    ws += (size_t)N * 64 * 4;
    float*    yb   = (float*)ws;    ws += (size_t)N * 64 * 4;
    unsigned* aggf = (unsigned*)ws; ws += (size_t)N * 64 * 4;
    float* C2 = (float*)ws; ws += 4096 * 4;
    float* C3 = (float*)ws; ws += 4096 * 4;
    float* vv = (float*)ws; ws += 64 * 4;

    const int gemmBlocks  = (N + 255) / 256;
    const int edgeBlocks  = (E + 15) / 16;
    const int clearN4     = N * 16;             // N*64 uints / 4
    const int clearBlocks = (clearN4 + 255) / 256;

    prep_k<<<3, 256, 0, stream>>>(Wp, Wt, Wout, C2, C3, vv);

    // layer 1
    gemm64_k<false><<<gemmBlocks, 256, 0, stream>>>(x, nullptr, nullptr, Wp, ya, N);
    clear_k<<<clearBlocks, 256, 0, stream>>>(aggf, clearN4);
    edge_max_k<<<edgeBlocks, 256, 0, stream>>>(edges, ya, aggf, E);

    // layer 2
    gemm64_k<true><<<gemmBlocks, 256, 0, stream>>>(nullptr, aggf, ya, C2, yb, N);
    clear_k<<<clearBlocks, 256, 0, stream>>>(aggf, clearN4);
    edge_max_k<<<edgeBlocks, 256, 0, stream>>>(edges, yb, aggf, E);

    // layer 3
    gemm64_k<true><<<gemmBlocks, 256, 0, stream>>>(nullptr, aggf, yb, C3, ya, N);
    clear_k<<<clearBlocks, 256, 0, stream>>>(aggf, clearN4);
    edge_max_k<<<edgeBlocks, 256, 0, stream>>>(edges, ya, aggf, E);

    // head
    final_k<<<gemmBlocks, 256, 0, stream>>>(aggf, ya, vv, bout, out, N);
}

// Round 2
// 480.139 us; speedup vs baseline: 6.9691x; 6.9691x over previous
//
#include <hip/hip_runtime.h>
#include <math.h>

// ---------------------------------------------------------------------------
// PointSampler / DevConv, CSR-gather formulation (no heavy atomics):
//   CSR build (once): deg histogram -> exclusive scan -> scatter src by dst
//   per layer l: y = h @ Cl.T              (Cl = Wp[l] @ Wt[l-1], C0 = Wp[0])
//                agg[i] = deg>0 ? (max_{j in N(i)} y[j]) - y[i] : 0
//   head:        out[i] = sigmoid( agg3[i] . v + b ),  v = (W_out @ Wt[2]).T
// max is order-independent in f32, so CSR slot order (atomicAdd) is harmless.
// ---------------------------------------------------------------------------

// block 0: C2 = Wp[1]@Wt[0];  block 1: C3 = Wp[2]@Wt[1];  block 2: v = Wout@Wt[2]
__global__ __launch_bounds__(256) void prep_k(
    const float* __restrict__ Wp, const float* __restrict__ Wt,
    const float* __restrict__ Wout,
    float* __restrict__ C2, float* __restrict__ C3, float* __restrict__ vout)
{
    __shared__ float A[4096];
    __shared__ float B[4096];
    int tid = threadIdx.x;
    int b = blockIdx.x;
    if (b < 2) {
        const float* Ap = Wp + (size_t)(b + 1) * 4096;
        const float* Bp = Wt + (size_t)b * 4096;
        for (int i = tid; i < 4096; i += 256) { A[i] = Ap[i]; B[i] = Bp[i]; }
        __syncthreads();
        float* C = b ? C3 : C2;
        for (int i = tid; i < 4096; i += 256) {
            int d = i >> 6, k = i & 63;
            float s = 0.f;
            #pragma unroll
            for (int m = 0; m < 64; ++m) s += A[d * 64 + m] * B[m * 64 + k];
            C[i] = s;
        }
    } else {
        for (int i = tid; i < 4096; i += 256) A[i] = Wt[2 * 4096 + i];
        if (tid < 64) B[tid] = Wout[tid];
        __syncthreads();
        if (tid < 64) {
            float s = 0.f;
            #pragma unroll
            for (int m = 0; m < 64; ++m) s += B[m] * A[m * 64 + tid];
            vout[tid] = s;
        }
    }
}

// ---------------- CSR build ----------------

__global__ __launch_bounds__(256) void clear_int_k(int* __restrict__ p, int n)
{
    int i = blockIdx.x * 256 + threadIdx.x;
    if (i < n) p[i] = 0;
}

__global__ __launch_bounds__(256) void hist_k(
    const int* __restrict__ eidx, int* __restrict__ deg, int E)
{
    int e = blockIdx.x * 256 + threadIdx.x;
    if (e < E) atomicAdd(&deg[eidx[E + e]], 1);
}

// per-256-chunk inclusive scan
__global__ __launch_bounds__(256) void scan1_k(
    const int* __restrict__ deg, int* __restrict__ inc,
    int* __restrict__ bsum, int n)
{
    __shared__ int s[256];
    int tid = threadIdx.x;
    int i = blockIdx.x * 256 + tid;
    int v = (i < n) ? deg[i] : 0;
    s[tid] = v;
    __syncthreads();
    for (int off = 1; off < 256; off <<= 1) {
        int t = (tid >= off) ? s[tid - off] : 0;
        __syncthreads();
        s[tid] += t;
        __syncthreads();
    }
    if (i < n) inc[i] = s[tid];
    if (tid == 255) bsum[blockIdx.x] = s[255];
}

// single-block exclusive scan of block sums (nb <= 512)
__global__ __launch_bounds__(512) void scan2_k(int* __restrict__ bsum, int nb)
{
    __shared__ int s[512];
    int tid = threadIdx.x;
    int v = (tid < nb) ? bsum[tid] : 0;
    s[tid] = v;
    __syncthreads();
    for (int off = 1; off < 512; off <<= 1) {
        int t = (tid >= off) ? s[tid - off] : 0;
        __syncthreads();
        s[tid] += t;
        __syncthreads();
    }
    if (tid < nb) bsum[tid] = s[tid] - v;   // exclusive offset
}

__global__ __launch_bounds__(256) void scan3_k(
    const int* __restrict__ deg, const int* __restrict__ inc,
    const int* __restrict__ bsum, int* __restrict__ row_ptr,
    int* __restrict__ cursor, int n, int E)
{
    int i = blockIdx.x * 256 + threadIdx.x;
    if (i < n) {
        int ex = inc[i] - deg[i] + bsum[i >> 8];
        row_ptr[i] = ex;
        cursor[i]  = ex;
    }
    if (i == n) row_ptr[n] = E;
}

__global__ __launch_bounds__(256) void scatter_k(
    const int* __restrict__ eidx, int* __restrict__ cursor,
    int* __restrict__ col, int E)
{
    int e = blockIdx.x * 256 + threadIdx.x;
    if (e < E) {
        int src = eidx[e];
        int dst = eidx[E + e];
        int pos = atomicAdd(&cursor[dst], 1);
        col[pos] = src;
    }
}

// ---------------- per-layer kernels ----------------

// y[r][:] = in_row(r) @ C.T ; one thread per row, transposed weight in LDS.
__global__ __launch_bounds__(256) void gemm64_k(
    const float* __restrict__ in,
    const float* __restrict__ C,      // [64][64] row-major, C[d][k]
    float* __restrict__ out, int n)
{
    __shared__ float sCT[64 * 68];    // sCT[k*68 + d]
    int tid = threadIdx.x;
    for (int i = tid; i < 4096; i += 256) {
        int d = i >> 6, k = i & 63;
        sCT[k * 68 + d] = C[i];
    }
    __syncthreads();
    int r = blockIdx.x * 256 + tid;
    if (r >= n) return;

    float xr[64];
    const float4* xp = (const float4*)(in + (size_t)r * 64);
    #pragma unroll
    for (int k4 = 0; k4 < 16; ++k4) {
        float4 v = xp[k4];
        xr[k4 * 4 + 0] = v.x; xr[k4 * 4 + 1] = v.y;
        xr[k4 * 4 + 2] = v.z; xr[k4 * 4 + 3] = v.w;
    }

    float4* op = (float4*)(out + (size_t)r * 64);
    for (int dg = 0; dg < 16; ++dg) {
        float a0 = 0.f, a1 = 0.f, a2 = 0.f, a3 = 0.f;
        #pragma unroll
        for (int k = 0; k < 64; ++k) {
            float4 c = *(const float4*)&sCT[k * 68 + dg * 4];
            a0 += xr[k] * c.x;
            a1 += xr[k] * c.y;
            a2 += xr[k] * c.z;
            a3 += xr[k] * c.w;
        }
        float4 o; o.x = a0; o.y = a1; o.z = a2; o.w = a3;
        op[dg] = o;
    }
}

// one wave per node, lane = component; coalesced 256B row loads per neighbor.
__global__ __launch_bounds__(256) void gather_max_k(
    const int* __restrict__ row_ptr, const int* __restrict__ col,
    const float* __restrict__ y, float* __restrict__ agg, int n)
{
    int gid  = blockIdx.x * 256 + threadIdx.x;
    int node = gid >> 6;
    int lane = threadIdx.x & 63;
    if (node >= n) return;
    int beg = row_ptr[node], end = row_ptr[node + 1];

    float m0 = -INFINITY, m1 = -INFINITY, m2 = -INFINITY, m3 = -INFINITY;
    for (int base = beg; base < end; base += 64) {
        int idx = base + lane;
        int myc = (idx < end) ? col[idx] : 0;
        int cnt = min(64, end - base);
        int k = 0;
        for (; k + 4 <= cnt; k += 4) {
            int j0 = __shfl(myc, k);
            int j1 = __shfl(myc, k + 1);
            int j2 = __shfl(myc, k + 2);
            int j3 = __shfl(myc, k + 3);
            m0 = fmaxf(m0, y[(size_t)j0 * 64 + lane]);
            m1 = fmaxf(m1, y[(size_t)j1 * 64 + lane]);
            m2 = fmaxf(m2, y[(size_t)j2 * 64 + lane]);
            m3 = fmaxf(m3, y[(size_t)j3 * 64 + lane]);
        }
        for (; k < cnt; ++k) {
            int j = __shfl(myc, k);
            m0 = fmaxf(m0, y[(size_t)j * 64 + lane]);
        }
    }
    float m = fmaxf(fmaxf(m0, m1), fmaxf(m2, m3));
    float yi = y[(size_t)node * 64 + lane];
    agg[(size_t)node * 64 + lane] = (end > beg) ? (m - yi) : 0.f;
}

__global__ __launch_bounds__(256) void final_k(
    const float* __restrict__ agg, const float* __restrict__ v,
    const float* __restrict__ bptr, float* __restrict__ out, int n)
{
    __shared__ float sv[64];
    int tid = threadIdx.x;
    if (tid < 64) sv[tid] = v[tid];
    __syncthreads();
    int r = blockIdx.x * 256 + tid;
    if (r >= n) return;
    const float4* ap = (const float4*)(agg + (size_t)r * 64);
    float s = 0.f;
    #pragma unroll
    for (int k4 = 0; k4 < 16; ++k4) {
        float4 a = ap[k4];
        s += a.x * sv[k4 * 4 + 0] + a.y * sv[k4 * 4 + 1]
           + a.z * sv[k4 * 4 + 2] + a.w * sv[k4 * 4 + 3];
    }
    s += bptr[0];
    out[r] = 1.f / (1.f + __expf(-s));
}

extern "C" void kernel_launch(void* const* d_in, const int* in_sizes, int n_in,
                              void* d_out, int out_size, void* d_ws, size_t ws_size,
                              hipStream_t stream)
{
    const float* x     = (const float*)d_in[0];
    const int*   edges = (const int*)d_in[1];   // int32 view, [2][E]
    const float* Wp    = (const float*)d_in[2];
    const float* Wt    = (const float*)d_in[3];
    const float* Wout  = (const float*)d_in[4];
    const float* bout  = (const float*)d_in[5];
    const int N = in_sizes[0] / 64;             // 100000
    const int E = in_sizes[1] / 2;              // 1600000
    float* out = (float*)d_out;

    char* ws = (char*)d_ws;
    float* y    = (float*)ws; ws += (size_t)N * 64 * 4;
    float* agg  = (float*)ws; ws += (size_t)N * 64 * 4;
    int* deg     = (int*)ws; ws += (size_t)N * 4;
    int* inc     = (int*)ws; ws += (size_t)N * 4;
    int* row_ptr = (int*)ws; ws += (size_t)(N + 1) * 4;
    int* cursor  = (int*)ws; ws += (size_t)N * 4;
    int* bsum    = (int*)ws; ws += 512 * 4;
    int* col     = (int*)ws; ws += (size_t)E * 4;
    float* C2 = (float*)ws; ws += 4096 * 4;
    float* C3 = (float*)ws; ws += 4096 * 4;
    float* vv = (float*)ws; ws += 64 * 4;

    const int nodeBlocks  = (N + 255) / 256;
    const int edgeBlocks  = (E + 255) / 256;
    const int scanBlocks  = (N + 255) / 256;          // 391
    const int gatherBlocks = (N * 64 + 255) / 256;    // 25000

    prep_k<<<3, 256, 0, stream>>>(Wp, Wt, Wout, C2, C3, vv);

    // CSR build
    clear_int_k<<<nodeBlocks, 256, 0, stream>>>(deg, N);
    hist_k<<<edgeBlocks, 256, 0, stream>>>(edges, deg, E);
    scan1_k<<<scanBlocks, 256, 0, stream>>>(deg, inc, bsum, N);
    scan2_k<<<1, 512, 0, stream>>>(bsum, scanBlocks);
    scan3_k<<<(N + 256) / 256, 256, 0, stream>>>(deg, inc, bsum, row_ptr, cursor, N, E);
    scatter_k<<<edgeBlocks, 256, 0, stream>>>(edges, cursor, col, E);

    // layer 1
    gemm64_k<<<nodeBlocks, 256, 0, stream>>>(x, Wp, y, N);
    gather_max_k<<<gatherBlocks, 256, 0, stream>>>(row_ptr, col, y, agg, N);
    // layer 2
    gemm64_k<<<nodeBlocks, 256, 0, stream>>>(agg, C2, y, N);
    gather_max_k<<<gatherBlocks, 256, 0, stream>>>(row_ptr, col, y, agg, N);
    // layer 3
    gemm64_k<<<nodeBlocks, 256, 0, stream>>>(agg, C3, y, N);
    gather_max_k<<<gatherBlocks, 256, 0, stream>>>(row_ptr, col, y, agg, N);

    // head
    final_k<<<nodeBlocks, 256, 0, stream>>>(agg, vv, bout, out, N);
}

// Round 3
// 329.070 us; speedup vs baseline: 10.1684x; 1.4591x over previous
//
#include <hip/hip_runtime.h>
#include <math.h>

// ---------------------------------------------------------------------------
// PointSampler / DevConv, CSR-gather with bucketed (write-coalesced) CSR build:
//   bucket_hist -> bucket_scan -> partA (LDS-staged partition by dst>>9)
//                               -> partB (per-bucket degree count + scan +
//                                         LDS-staged col scatter, writes row_ptr)
//   per layer l: y = h @ Cl.T              (Cl = Wp[l] @ Wt[l-1], C0 = Wp[0])
//                agg[i] = deg>0 ? (max_{j in N(i)} y[j]) - y[i] : 0
//   head (fused into 3rd gather): out[i] = sigmoid( agg3[i] . v + b )
// max is order-independent in f32, so atomic slot ordering is harmless.
// ---------------------------------------------------------------------------

#define WBITS 9
#define WNODES 512            // nodes per bucket
#define MAXNB 256             // max buckets (requires N <= 131072, src < 2^17)
#define CHUNK 8192            // edges per partA/hist block
#define STG_CAP 12288         // partB LDS staging entries (48 KB)

// block 0: C2 = Wp[1]@Wt[0];  block 1: C3 = Wp[2]@Wt[1];  block 2: v = Wout@Wt[2]
__global__ __launch_bounds__(256) void prep_k(
    const float* __restrict__ Wp, const float* __restrict__ Wt,
    const float* __restrict__ Wout,
    float* __restrict__ C2, float* __restrict__ C3, float* __restrict__ vout)
{
    __shared__ float A[4096];
    __shared__ float B[4096];
    int tid = threadIdx.x;
    int b = blockIdx.x;
    if (b < 2) {
        const float* Ap = Wp + (size_t)(b + 1) * 4096;
        const float* Bp = Wt + (size_t)b * 4096;
        for (int i = tid; i < 4096; i += 256) { A[i] = Ap[i]; B[i] = Bp[i]; }
        __syncthreads();
        float* C = b ? C3 : C2;
        for (int i = tid; i < 4096; i += 256) {
            int d = i >> 6, k = i & 63;
            float s = 0.f;
            #pragma unroll
            for (int m = 0; m < 64; ++m) s += A[d * 64 + m] * B[m * 64 + k];
            C[i] = s;
        }
    } else {
        for (int i = tid; i < 4096; i += 256) A[i] = Wt[2 * 4096 + i];
        if (tid < 64) B[tid] = Wout[tid];
        __syncthreads();
        if (tid < 64) {
            float s = 0.f;
            #pragma unroll
            for (int m = 0; m < 64; ++m) s += B[m] * A[m * 64 + tid];
            vout[tid] = s;
        }
    }
}

__global__ __launch_bounds__(256) void clear_int_k(int* __restrict__ p, int n)
{
    int i = blockIdx.x * 256 + threadIdx.x;
    if (i < n) p[i] = 0;
}

// per-chunk LDS histogram of dst buckets -> global bucket counts
__global__ __launch_bounds__(256) void bucket_hist_k(
    const int* __restrict__ eidx, int* __restrict__ bcnt, int E, int NB)
{
    __shared__ int h[MAXNB];
    int tid = threadIdx.x;
    for (int i = tid; i < NB; i += 256) h[i] = 0;
    __syncthreads();
    int start = blockIdx.x * CHUNK;
    int end = min(E, start + CHUNK);
    for (int e = start + tid; e < end; e += 256)
        atomicAdd(&h[eidx[E + e] >> WBITS], 1);
    __syncthreads();
    for (int i = tid; i < NB; i += 256)
        if (h[i]) atomicAdd(&bcnt[i], h[i]);
}

// 1-block scan of bucket counts -> bbase (exclusive), init gcur, row_ptr[N]=E
__global__ __launch_bounds__(256) void bucket_scan_k(
    const int* __restrict__ bcnt, int* __restrict__ bbase,
    int* __restrict__ gcur, int* __restrict__ row_ptr, int NB, int N, int E)
{
    __shared__ int sA[MAXNB], sB[MAXNB];
    int tid = threadIdx.x;
    int v0 = (tid < NB) ? bcnt[tid] : 0;
    sA[tid] = v0;
    __syncthreads();
    int* sp = sA; int* dp = sB;
    for (int off = 1; off < MAXNB; off <<= 1) {
        dp[tid] = sp[tid] + ((tid >= off) ? sp[tid - off] : 0);
        __syncthreads();
        int* t = sp; sp = dp; dp = t;
    }
    if (tid < NB) {
        int ex = sp[tid] - v0;
        bbase[tid] = ex;
        gcur[tid]  = ex;
    }
    if (tid == 0) {
        bbase[NB]  = E;
        row_ptr[N] = E;
    }
}

// partition edges into bucket-major order (packed src | dstLow<<17)
__global__ __launch_bounds__(256) void partA_k(
    const int* __restrict__ eidx, int* __restrict__ gcur,
    int* __restrict__ B1, int E, int NB)
{
    __shared__ int hist[MAXNB];
    __shared__ int lofs[MAXNB];
    __shared__ int lcur[MAXNB];
    __shared__ int gofs[MAXNB];
    __shared__ int sA[MAXNB], sB[MAXNB];
    __shared__ int stg_val[CHUNK];
    __shared__ int stg_pos[CHUNK];
    int tid = threadIdx.x;
    int start = blockIdx.x * CHUNK;
    int cnt = min(E - start, CHUNK);
    if (cnt <= 0) return;

    for (int i = tid; i < NB; i += 256) hist[i] = 0;
    __syncthreads();

    int es[CHUNK / 256], ed[CHUNK / 256];
    #pragma unroll
    for (int i = 0; i < CHUNK / 256; ++i) {
        int li = i * 256 + tid;
        if (li < cnt) {
            es[i] = eidx[start + li];
            ed[i] = eidx[E + start + li];
            atomicAdd(&hist[ed[i] >> WBITS], 1);
        }
    }
    __syncthreads();
    sA[tid] = (tid < NB) ? hist[tid] : 0;
    __syncthreads();
    int* sp = sA; int* dp = sB;
    for (int off = 1; off < MAXNB; off <<= 1) {
        dp[tid] = sp[tid] + ((tid >= off) ? sp[tid - off] : 0);
        __syncthreads();
        int* t = sp; sp = dp; dp = t;
    }
    if (tid < NB) {
        int c  = hist[tid];
        int ex = sp[tid] - c;
        lofs[tid] = ex;
        lcur[tid] = ex;
        gofs[tid] = c ? atomicAdd(&gcur[tid], c) : 0;
    }
    __syncthreads();
    #pragma unroll
    for (int i = 0; i < CHUNK / 256; ++i) {
        int li = i * 256 + tid;
        if (li < cnt) {
            int b = ed[i] >> WBITS;
            int p = atomicAdd(&lcur[b], 1);
            stg_val[p] = es[i] | ((ed[i] & (WNODES - 1)) << 17);
            stg_pos[p] = gofs[b] + (p - lofs[b]);
        }
    }
    __syncthreads();
    for (int i = tid; i < cnt; i += 256)
        B1[stg_pos[i]] = stg_val[i];
}

// per-bucket: degree count -> scan -> row_ptr; LDS-staged coalesced col scatter
__global__ __launch_bounds__(256) void partB_k(
    const int* __restrict__ B1, const int* __restrict__ bbase,
    int* __restrict__ row_ptr, int* __restrict__ col, int N, int NB)
{
    __shared__ int cnt[WNODES];
    __shared__ int lcur[WNODES];
    __shared__ int sA[WNODES], sB[WNODES];
    __shared__ int stg[STG_CAP];
    int b   = blockIdx.x;
    int tid = threadIdx.x;
    int gb0 = bbase[b], gb1 = bbase[b + 1];
    int m   = gb1 - gb0;
    int nb0 = b << WBITS;

    for (int i = tid; i < WNODES; i += 256) cnt[i] = 0;
    __syncthreads();
    for (int i = tid; i < m; i += 256)
        atomicAdd(&cnt[B1[gb0 + i] >> 17], 1);
    __syncthreads();
    for (int i = tid; i < WNODES; i += 256) sA[i] = cnt[i];
    __syncthreads();
    int* sp = sA; int* dp = sB;
    for (int off = 1; off < WNODES; off <<= 1) {
        for (int i = tid; i < WNODES; i += 256)
            dp[i] = sp[i] + ((i >= off) ? sp[i - off] : 0);
        __syncthreads();
        int* t = sp; sp = dp; dp = t;
    }
    for (int i = tid; i < WNODES; i += 256) {
        int ex = sp[i] - cnt[i];
        lcur[i] = ex;
        int node = nb0 + i;
        if (node < N) row_ptr[node] = gb0 + ex;
    }
    __syncthreads();
    if (m <= STG_CAP) {
        for (int i = tid; i < m; i += 256) {
            int v = B1[gb0 + i];
            int p = atomicAdd(&lcur[v >> 17], 1);
            stg[p] = v & 0x1FFFF;
        }
        __syncthreads();
        for (int i = tid; i < m; i += 256)
            col[gb0 + i] = stg[i];
    } else {               // adversarial-degree fallback (correct, uncoalesced)
        for (int i = tid; i < m; i += 256) {
            int v = B1[gb0 + i];
            int p = atomicAdd(&lcur[v >> 17], 1);
            col[gb0 + p] = v & 0x1FFFF;
        }
    }
}

// ---------------- per-layer kernels ----------------

// y[r][:] = in_row(r) @ C.T ; one thread per row, transposed weight in LDS.
__global__ __launch_bounds__(256) void gemm64_k(
    const float* __restrict__ in,
    const float* __restrict__ C,      // [64][64] row-major, C[d][k]
    float* __restrict__ out, int n)
{
    __shared__ float sCT[64 * 68];    // sCT[k*68 + d]
    int tid = threadIdx.x;
    for (int i = tid; i < 4096; i += 256) {
        int d = i >> 6, k = i & 63;
        sCT[k * 68 + d] = C[i];
    }
    __syncthreads();
    int r = blockIdx.x * 256 + tid;
    if (r >= n) return;

    float xr[64];
    const float4* xp = (const float4*)(in + (size_t)r * 64);
    #pragma unroll
    for (int k4 = 0; k4 < 16; ++k4) {
        float4 v = xp[k4];
        xr[k4 * 4 + 0] = v.x; xr[k4 * 4 + 1] = v.y;
        xr[k4 * 4 + 2] = v.z; xr[k4 * 4 + 3] = v.w;
    }

    float4* op = (float4*)(out + (size_t)r * 64);
    for (int dg = 0; dg < 16; ++dg) {
        float a0 = 0.f, a1 = 0.f, a2 = 0.f, a3 = 0.f;
        #pragma unroll
        for (int k = 0; k < 64; ++k) {
            float4 c = *(const float4*)&sCT[k * 68 + dg * 4];
            a0 += xr[k] * c.x;
            a1 += xr[k] * c.y;
            a2 += xr[k] * c.z;
            a3 += xr[k] * c.w;
        }
        float4 o; o.x = a0; o.y = a1; o.z = a2; o.w = a3;
        op[dg] = o;
    }
}

// one wave per node, lane = component; coalesced 256B row loads per neighbor.
// FINAL: fuse the Linear(D,1)+sigmoid head (wave shfl-reduce dot).
template<bool FINAL>
__global__ __launch_bounds__(256) void gather_max_k(
    const int* __restrict__ row_ptr, const int* __restrict__ col,
    const float* __restrict__ y, float* __restrict__ agg,
    const float* __restrict__ v, const float* __restrict__ bptr,
    float* __restrict__ out, int n)
{
    int gid  = blockIdx.x * 256 + threadIdx.x;
    int node = gid >> 6;
    int lane = threadIdx.x & 63;
    if (node >= n) return;
    int beg = row_ptr[node], end = row_ptr[node + 1];

    float m0 = -INFINITY, m1 = -INFINITY, m2 = -INFINITY, m3 = -INFINITY;
    for (int base = beg; base < end; base += 64) {
        int idx = base + lane;
        int myc = (idx < end) ? col[idx] : 0;
        int cnt = min(64, end - base);
        int k = 0;
        for (; k + 4 <= cnt; k += 4) {
            int j0 = __shfl(myc, k);
            int j1 = __shfl(myc, k + 1);
            int j2 = __shfl(myc, k + 2);
            int j3 = __shfl(myc, k + 3);
            m0 = fmaxf(m0, y[(size_t)j0 * 64 + lane]);
            m1 = fmaxf(m1, y[(size_t)j1 * 64 + lane]);
            m2 = fmaxf(m2, y[(size_t)j2 * 64 + lane]);
            m3 = fmaxf(m3, y[(size_t)j3 * 64 + lane]);
        }
        for (; k < cnt; ++k) {
            int j = __shfl(myc, k);
            m0 = fmaxf(m0, y[(size_t)j * 64 + lane]);
        }
    }
    float m = fmaxf(fmaxf(m0, m1), fmaxf(m2, m3));
    float yi = y[(size_t)node * 64 + lane];
    float a  = (end > beg) ? (m - yi) : 0.f;
    if (!FINAL) {
        agg[(size_t)node * 64 + lane] = a;
    } else {
        float t = a * v[lane];
        #pragma unroll
        for (int off = 32; off >= 1; off >>= 1)
            t += __shfl_xor(t, off);
        if (lane == 0)
            out[node] = 1.f / (1.f + __expf(-(t + bptr[0])));
    }
}

extern "C" void kernel_launch(void* const* d_in, const int* in_sizes, int n_in,
                              void* d_out, int out_size, void* d_ws, size_t ws_size,
                              hipStream_t stream)
{
    const float* x     = (const float*)d_in[0];
    const int*   edges = (const int*)d_in[1];   // int32 view, [2][E]
    const float* Wp    = (const float*)d_in[2];
    const float* Wt    = (const float*)d_in[3];
    const float* Wout  = (const float*)d_in[4];
    const float* bout  = (const float*)d_in[5];
    const int N = in_sizes[0] / 64;             // 100000
    const int E = in_sizes[1] / 2;              // 1600000
    const int NB = (N + WNODES - 1) >> WBITS;   // 196
    float* out = (float*)d_out;

    char* ws = (char*)d_ws;
    float* y    = (float*)ws; ws += (size_t)N * 64 * 4;
    float* agg  = (float*)ws; ws += (size_t)N * 64 * 4;
    int*   B1   = (int*)agg;                    // alias: B1 dead before agg live
    int* col     = (int*)ws; ws += (size_t)E * 4;
    int* row_ptr = (int*)ws; ws += (size_t)(N + 4) * 4;
    int* bcnt    = (int*)ws; ws += MAXNB * 4;
    int* bbase   = (int*)ws; ws += (MAXNB + 4) * 4;
    int* gcur    = (int*)ws; ws += MAXNB * 4;
    float* C2 = (float*)ws; ws += 4096 * 4;
    float* C3 = (float*)ws; ws += 4096 * 4;
    float* vv = (float*)ws; ws += 64 * 4;

    const int nodeBlocks   = (N + 255) / 256;
    const int chunkBlocks  = (E + CHUNK - 1) / CHUNK;
    const int gatherBlocks = (N * 64 + 255) / 256;

    prep_k<<<3, 256, 0, stream>>>(Wp, Wt, Wout, C2, C3, vv);

    // CSR build (bucketed, write-coalesced)
    clear_int_k<<<1, 256, 0, stream>>>(bcnt, NB);
    bucket_hist_k<<<chunkBlocks, 256, 0, stream>>>(edges, bcnt, E, NB);
    bucket_scan_k<<<1, 256, 0, stream>>>(bcnt, bbase, gcur, row_ptr, NB, N, E);
    partA_k<<<chunkBlocks, 256, 0, stream>>>(edges, gcur, B1, E, NB);
    partB_k<<<NB, 256, 0, stream>>>(B1, bbase, row_ptr, col, N, NB);

    // layer 1
    gemm64_k<<<nodeBlocks, 256, 0, stream>>>(x, Wp, y, N);
    gather_max_k<false><<<gatherBlocks, 256, 0, stream>>>(row_ptr, col, y, agg,
                                                          nullptr, nullptr, nullptr, N);
    // layer 2
    gemm64_k<<<nodeBlocks, 256, 0, stream>>>(agg, C2, y, N);
    gather_max_k<false><<<gatherBlocks, 256, 0, stream>>>(row_ptr, col, y, agg,
                                                          nullptr, nullptr, nullptr, N);
    // layer 3
    gemm64_k<<<nodeBlocks, 256, 0, stream>>>(agg, C3, y, N);
    gather_max_k<true><<<gatherBlocks, 256, 0, stream>>>(row_ptr, col, y, nullptr,
                                                         vv, bout, out, N);
}